// Round 7
// baseline (411.151 us; speedup 1.0000x reference)
//
#include <hip/hip_runtime.h>

typedef unsigned short u16;
typedef unsigned int   u32;
typedef __attribute__((ext_vector_type(8))) short bf16x8;
typedef __attribute__((ext_vector_type(4))) float f32x4;

#define NB 131072               // batch rows
#define LN_EPS 1e-5f
#define EX_STRIDE 136           // 128 + 8 pad (bf16 elems) -> benign aliasing (measured ~0 conflicts)

// Native RNE fp32->bf16 (compiler emits packed cvt on gfx950)
__device__ __forceinline__ u16 f2b(float f){
  union { __bf16 h; u16 u; } c; c.h = (__bf16)f; return c.u;
}
__device__ __forceinline__ float upk(u32 pr, int hi){
  union { u32 u; float f; } c; c.u = hi ? (pr & 0xFFFF0000u) : (pr << 16); return c.f;
}
__device__ __forceinline__ float rowsum16(float x){
  x += __shfl_xor(x, 1);
  x += __shfl_xor(x, 2);
  x += __shfl_xor(x, 4);
  x += __shfl_xor(x, 8);
  return x;
}
// 8 consecutive fp32 -> bf16x8 A-fragment chunk
__device__ __forceinline__ bf16x8 cvt8(const float* __restrict__ s){
  f32x4 x0 = *(const f32x4*)s;
  f32x4 x1 = *(const f32x4*)(s + 4);
  bf16x8 r;
  r[0]=(short)f2b(x0[0]); r[1]=(short)f2b(x0[1]);
  r[2]=(short)f2b(x0[2]); r[3]=(short)f2b(x0[3]);
  r[4]=(short)f2b(x1[0]); r[5]=(short)f2b(x1[1]);
  r[6]=(short)f2b(x1[2]); r[7]=(short)f2b(x1[3]);
  return r;
}

// async global->LDS, 16 B per lane (dest = uniform base + lane*16, src per-lane)
__device__ __forceinline__ void glds16(const u16* g, u16* l){
  __builtin_amdgcn_global_load_lds(
      (const __attribute__((address_space(1))) void*)g,
      (__attribute__((address_space(3))) void*)l, 16, 0, 0);
}
// Stage one 128x128 bf16 B matrix (32 KiB, fragment-order = lane-linear) into LDS.
// Completion = next __syncthreads() (its vmcnt(0) drain is the staging wait).
__device__ __forceinline__ void stageB(const u16* __restrict__ packB, int m,
                                       u16* __restrict__ bst, int wave, int lane){
  const u16* src = packB + m*16384 + wave*512 + lane*8;
  u16*       dst = bst   + wave*512;          // wave-uniform; HW adds lane*16B
  #pragma unroll
  for (int k = 0; k < 8; k++)
    glds16(src + k*2048, dst + k*2048);
}

// 16x128 @ 128x128 GEMM: A frags (4 K-tiles) vs B fragments staged in LDS.
__device__ __forceinline__ void gemm16(const bf16x8 a[4], const u16* __restrict__ Blds,
                                       int lane, f32x4 C[8]){
  const bf16x8* Bf = (const bf16x8*)Blds;
  #pragma unroll
  for (int nt = 0; nt < 8; nt++){
    f32x4 c = {0.f, 0.f, 0.f, 0.f};
    #pragma unroll
    for (int kt = 0; kt < 4; kt++){
      bf16x8 b = Bf[(nt*4 + kt)*64 + lane];   // ds_read_b128, contiguous
      c = __builtin_amdgcn_mfma_f32_16x16x32_bf16(a[kt], b, c, 0, 0, 0);
    }
    C[nt] = c;
  }
}

// ---------------- prep: pack weights (fp32 -> bf16, gamma FOLDED) + fp32 vectors ----
// packB layout: mat m (0..11), fragment fi = nt*4+kt, lane, j:
//   packB[m*16384 + fi*512 + lane*8 + j] = Bg[k][n],  k = kt*32+(lane>>4)*8+j, n = nt*16+(lane&15)
// mats 0..5 (fwd, X @ W^T):  Bg[k][n] = src[n*128+k]   (mats 1-4: * gamma[k])
// mats 6..11 (bwd, G @ W):   Bg[k][n] = src[k*128+n]   (mats 7-10: * gamma[n])
// vecs: [0..511] sin embed, [512..1023] b' = bl + Wl@beta, [1024..1151] b_in,
//       [1152..1279] b_out
__global__ void prep_kernel(const float* __restrict__ t,   const float* __restrict__ W_in,
                            const float* __restrict__ b_in,const float* __restrict__ fw,
                            const float* __restrict__ fb,  const float* __restrict__ gamma,
                            const float* __restrict__ beta,const float* __restrict__ Wl,
                            const float* __restrict__ bl,  const float* __restrict__ W_out,
                            const float* __restrict__ b_out,
                            u16* __restrict__ packB, float* __restrict__ vecs)
{
  int bid = blockIdx.x, tid = threadIdx.x;
  if (bid < 768){
    int e    = bid*256 + tid;       // 0..196607
    int m    = e >> 14;             // matrix 0..11
    int r    = e & 16383;
    int fi   = r >> 9;              // nt*4+kt
    int lane = (r >> 3) & 63;
    int j    = r & 7;
    int nt = fi >> 2, kt = fi & 3;
    int k = kt*32 + (lane >> 4)*8 + j;
    int n = nt*16 + (lane & 15);
    const float* src; bool tr;
    if      (m == 0){ src = W_in;              tr = true;  }
    else if (m <= 4){ src = Wl + (m-1)*16384;  tr = true;  }
    else if (m == 5){ src = W_out;             tr = true;  }
    else if (m == 6){ src = W_out;             tr = false; }
    else if (m <=10){ src = Wl + (m-7)*16384;  tr = false; }
    else            { src = W_in;              tr = false; }
    float v = tr ? src[n*128 + k] : src[k*128 + n];
    if      (m >= 1 && m <= 4)  v *= gamma[(m-1)*128 + k];   // fwd: scale contraction dim
    else if (m >= 7 && m <= 10) v *= gamma[(m-7)*128 + n];   // bwd: scale output dim
    packB[e] = f2b(v);
  } else if (bid < 770){
    int idx = (bid - 768)*256 + tid;   // 0..511: time embed
    vecs[idx] = sinf(t[0] * fw[idx] + fb[idx]);
  } else if (bid < 772){
    int gid = (bid - 770)*256 + tid;   // 0..511: b'[i][o] = bl[i][o] + sum_k beta[i][k]*Wl[i][o][k]
    int i = gid >> 7, o = gid & 127;
    const float* Wr = Wl + i*16384 + o*128;
    const float* be = beta + i*128;
    float acc = bl[gid];
    for (int k2 = 0; k2 < 128; k2++) acc += be[k2] * Wr[k2];
    vecs[512 + gid] = acc;
  } else {
    if (tid < 128) vecs[1024 + tid]        = b_in[tid];
    else           vecs[1152 + (tid-128)]  = b_out[tid-128];
  }
}

// ---------------- fused forward + VJP ----------------
// Round 10 == round-9 kernel resubmitted verbatim (round-9 bench died on the
// same infra failure as round 2; source re-audited clean: LDS 54272<=54613
// for 3 blocks/CU, gamma/beta fold algebra verified, bwd schedule verified).
// r4/r5 calibration: unified VGPR+AGPR ~512/wave-slot; trims to reach
// 3 waves/SIMD without spill:
// (1) gamma folded into packB, beta into b' (prep) -> sv = 4 KiB LDS, fewer
//     epilogue ops; sv STAYS in LDS (r5 lesson). b_in/b_out from global.
// (2) mus/invs checkpoint dropped (-32 regs): bwd recomputes LN stats from
//     sp_ck in one pass (mean(gx*xh) = inv*(mgs - mu*m1)).
// Core state ~160 unified <= 168 budget of (256,3). Spill tripwire:
// hbm_bytes must stay ~2.2e8.
__global__ __launch_bounds__(256, 3)
void fused_vf(const float* __restrict__ p, const float* __restrict__ w,
              const u16* __restrict__ packB, const float* __restrict__ vecs,
              float* __restrict__ dp_out, float* __restrict__ dw_out)
{
  __shared__ __align__(16) u16  exch[4 * 16 * EX_STRIDE];
  __shared__ __align__(16) u16  bstage[16384];
  __shared__ float sv[1024];

  const int tid  = threadIdx.x;
  const int wave = tid >> 6, lane = tid & 63;
  const int l15  = lane & 15, quad = lane >> 4;
  u16* ex = exch + wave * 16 * EX_STRIDE;

  stageB(packB, 0, bstage, wave, lane);          // B0 in flight
  for (int idx = tid; idx < 1024; idx += 256) sv[idx] = vecs[idx];
  const float* sS   = sv;          // [4][128] sin embed
  const float* sBl  = sv + 512;    // [4][128] b' (beta folded)
  const float* gBin  = vecs + 1024; // [128] global (used once)
  const float* gBout = vecs + 1152; // [128] global (used once)

  const long rowBase = (long)blockIdx.x * 64 + wave * 16;

  // backward checkpoint: sp only (LN stats recomputed in bwd)
  u32   sp_ck[4][8][2];  // sp_i bf16-packed along C reg dim (64 regs)

  bf16x8 a[4];
  f32x4  C[8];

  // ---- forward: h0 = p @ W_in^T + b_in ----
  {
    const float* pr = p + (size_t)(rowBase + l15)*128 + quad*8;
    #pragma unroll
    for (int kt = 0; kt < 4; kt++) a[kt] = cvt8(pr + kt*32);
  }
  __syncthreads();                               // sv + B0 staged
  gemm16(a, bstage, lane, C);
  #pragma unroll
  for (int nt = 0; nt < 8; nt++){
    float bv = gBin[nt*16 + l15];                // 8 global loads, once per kernel
    #pragma unroll
    for (int r = 0; r < 4; r++) C[nt][r] += bv;
  }

  // ---- forward layers ----
  #pragma unroll
  for (int i = 0; i < 4; i++){
    __syncthreads();                             // A: bstage reads done
    stageB(packB, 1+i, bstage, wave, lane);      // next B hides under compute
    float sum[4] = {0,0,0,0}, ssq[4] = {0,0,0,0};
    #pragma unroll
    for (int nt = 0; nt < 8; nt++){
      float se = sS[i*128 + nt*16 + l15];
      #pragma unroll
      for (int r = 0; r < 4; r++){
        float x  = C[nt][r] + se;                 // a_i
        float e  = __expf(-fabsf(x));
        float li = __logf(1.0f + e);
        float sp = fmaxf(x, 0.0f) + li;           // softplus
        u16 sb = f2b(sp);                         // checkpoint sp
        if (r & 1) sp_ck[i][nt][r>>1] |= ((u32)sb) << 16; else sp_ck[i][nt][r>>1] = sb;
        sum[r] += sp; ssq[r] += sp*sp;
        C[nt][r] = sp;                            // u_i in place
      }
    }
    float mu[4], inv[4];
    #pragma unroll
    for (int r = 0; r < 4; r++){
      float m1 = rowsum16(sum[r]) * (1.0f/128.0f);
      float m2 = rowsum16(ssq[r]) * (1.0f/128.0f);
      float var = m2 - m1*m1;
      mu[r] = m1; inv[r] = rsqrtf(fmaxf(var, 0.0f) + LN_EPS);
    }
    #pragma unroll
    for (int nt = 0; nt < 8; nt++)
      #pragma unroll
      for (int r = 0; r < 4; r++){
        float xh = (C[nt][r] - mu[r]) * inv[r];   // gamma/beta folded into B/b'
        ex[(quad*4 + r)*EX_STRIDE + nt*16 + l15] = f2b(xh);
      }
    __syncthreads();                             // B: exch + staging ready
    {
      const u16* rp = ex + l15*EX_STRIDE + quad*8;
      #pragma unroll
      for (int kt = 0; kt < 4; kt++) a[kt] = *(const bf16x8*)(rp + kt*32);
    }
    gemm16(a, bstage, lane, C);
    #pragma unroll
    for (int nt = 0; nt < 8; nt++){
      float bv = sBl[i*128 + nt*16 + l15];        // b' = bl + Wl@beta
      #pragma unroll
      for (int r = 0; r < 4; r++) C[nt][r] += bv;
    }
  }

  // ---- forward head: dp = h4 @ W_out^T + b_out ----
  __syncthreads();                               // A
  stageB(packB, 5, bstage, wave, lane);
  #pragma unroll
  for (int nt = 0; nt < 8; nt++)
    #pragma unroll
    for (int r = 0; r < 4; r++)
      ex[(quad*4 + r)*EX_STRIDE + nt*16 + l15] = f2b(C[nt][r]);
  __syncthreads();                               // B
  {
    const u16* rp = ex + l15*EX_STRIDE + quad*8;
    #pragma unroll
    for (int kt = 0; kt < 4; kt++) a[kt] = *(const bf16x8*)(rp + kt*32);
  }
  gemm16(a, bstage, lane, C);
  {
    float* gp = dp_out + (size_t)rowBase*128;
    #pragma unroll
    for (int nt = 0; nt < 8; nt++){
      float bv = gBout[nt*16 + l15];
      #pragma unroll
      for (int r = 0; r < 4; r++)
        gp[(size_t)(quad*4 + r)*128 + nt*16 + l15] = C[nt][r] + bv;
    }
  }

  // ---- backward: g_h4 = w @ W_out ----
  __syncthreads();                               // A
  stageB(packB, 6, bstage, wave, lane);
  {
    const float* wr = w + (size_t)(rowBase + l15)*128 + quad*8;
    #pragma unroll
    for (int kt = 0; kt < 4; kt++) a[kt] = cvt8(wr + kt*32);
  }
  __syncthreads();                               // B (w-load latency covered staging)
  gemm16(a, bstage, lane, C);
  __syncthreads();                               // A
  stageB(packB, 10, bstage, wave, lane);         // first bwd-layer B

  #pragma unroll
  for (int ii = 0; ii < 4; ii++){
    const int i = 3 - ii;
    #pragma unroll
    for (int nt = 0; nt < 8; nt++)
      #pragma unroll
      for (int r = 0; r < 4; r++)
        ex[(quad*4 + r)*EX_STRIDE + nt*16 + l15] = f2b(C[nt][r]);
    __syncthreads();                             // B: exch + staging ready
    {
      const u16* rp = ex + l15*EX_STRIDE + quad*8;
      #pragma unroll
      for (int kt = 0; kt < 4; kt++) a[kt] = *(const bf16x8*)(rp + kt*32);
    }
    gemm16(a, bstage, lane, C);                  // g_xh = g_h @ (Wl*gamma)  [folded]
    __syncthreads();                             // A: bstage reads done
    stageB(packB, (ii < 3) ? (7 + (2 - ii)) : 11, bstage, wave, lane);
    // LN backward, stats recomputed from sp_ck (one stat-free pass):
    //   mu,inv from sum_sp/sum_sp2; m1 = mean(gx); mgs = mean(gx*sp);
    //   mean(gx*xh) = inv*(mgs - mu*m1)
    float ssp[4] = {0,0,0,0}, ss2[4] = {0,0,0,0};
    float s1[4]  = {0,0,0,0}, sgs[4] = {0,0,0,0};
    #pragma unroll
    for (int nt = 0; nt < 8; nt++)
      #pragma unroll
      for (int r = 0; r < 4; r++){
        float sp = upk(sp_ck[i][nt][r>>1], r & 1);
        float gx = C[nt][r];                      // g_xhat (direct, gamma folded)
        ssp[r] += sp; ss2[r] += sp*sp;
        s1[r]  += gx; sgs[r] += gx*sp;
      }
    float mu[4], inv[4], m1[4], m2[4];
    #pragma unroll
    for (int r = 0; r < 4; r++){
      float sm  = rowsum16(ssp[r]) * (1.0f/128.0f);
      float sq  = rowsum16(ss2[r]) * (1.0f/128.0f);
      float var = sq - sm*sm;
      float iv  = rsqrtf(fmaxf(var, 0.0f) + LN_EPS);
      float g1  = rowsum16(s1[r])  * (1.0f/128.0f);
      float ggs = rowsum16(sgs[r]) * (1.0f/128.0f);
      mu[r] = sm; inv[r] = iv; m1[r] = g1;
      m2[r] = iv * (ggs - sm*g1);                 // mean(gx*xh)
    }
    #pragma unroll
    for (int nt = 0; nt < 8; nt++)
      #pragma unroll
      for (int r = 0; r < 4; r++){
        float sp = upk(sp_ck[i][nt][r>>1], r & 1);
        float xh = (sp - mu[r]) * inv[r];
        float sg = 1.0f - __expf(-sp);            // sigmoid(a) = 1 - exp(-softplus(a))
        float gu = inv[r] * (C[nt][r] - m1[r] - xh * m2[r]);
        C[nt][r] = gu * sg;                       // g_a == g_h(prev layer)
      }
  }

  // ---- backward tail: g_p = g @ W_in ; dw = -g_p ----
  #pragma unroll
  for (int nt = 0; nt < 8; nt++)
    #pragma unroll
    for (int r = 0; r < 4; r++)
      ex[(quad*4 + r)*EX_STRIDE + nt*16 + l15] = f2b(C[nt][r]);
  __syncthreads();                               // B: exch + staging(11) ready
  {
    const u16* rp = ex + l15*EX_STRIDE + quad*8;
    #pragma unroll
    for (int kt = 0; kt < 4; kt++) a[kt] = *(const bf16x8*)(rp + kt*32);
  }
  gemm16(a, bstage, lane, C);
  {
    float* gp = dw_out + (size_t)rowBase*128;
    #pragma unroll
    for (int nt = 0; nt < 8; nt++)
      #pragma unroll
      for (int r = 0; r < 4; r++)
        gp[(size_t)(quad*4 + r)*128 + nt*16 + l15] = -C[nt][r];
  }
}

extern "C" void kernel_launch(void* const* d_in, const int* in_sizes, int n_in,
                              void* d_out, int out_size, void* d_ws, size_t ws_size,
                              hipStream_t stream)
{
  const float* t     = (const float*)d_in[0];
  const float* p     = (const float*)d_in[1];
  const float* w     = (const float*)d_in[2];
  const float* W_in  = (const float*)d_in[3];
  const float* b_in  = (const float*)d_in[4];
  const float* fw    = (const float*)d_in[5];
  const float* fb    = (const float*)d_in[6];
  const float* gamma = (const float*)d_in[7];
  const float* beta  = (const float*)d_in[8];
  const float* Wl    = (const float*)d_in[9];
  const float* bl    = (const float*)d_in[10];
  const float* W_out = (const float*)d_in[11];
  const float* b_out = (const float*)d_in[12];

  u16*   packB = (u16*)d_ws;                           // 12*16384 bf16 = 384 KiB
  float* vecs  = (float*)((char*)d_ws + 12*16384*2);   // 1280 fp32

  prep_kernel<<<773, 256, 0, stream>>>(t, W_in, b_in, fw, fb, gamma, beta,
                                       Wl, bl, W_out, b_out, packB, vecs);

  float* dp = (float*)d_out;
  float* dw = (float*)d_out + (size_t)NB * 128;
  fused_vf<<<NB/64, 256, 0, stream>>>(p, w, packB, vecs, dp, dw);
}

// Round 8
// 386.036 us; speedup vs baseline: 1.0651x; 1.0651x over previous
//
#include <hip/hip_runtime.h>

typedef unsigned short u16;
typedef unsigned int   u32;
typedef __attribute__((ext_vector_type(8))) short bf16x8;
typedef __attribute__((ext_vector_type(4))) float f32x4;

#define NB 131072               // batch rows
#define LN_EPS 1e-5f
#define EX_STRIDE 136           // 128 + 8 pad (bf16 elems) -> benign aliasing

// Native RNE fp32->bf16 (compiler emits packed cvt on gfx950)
__device__ __forceinline__ u16 f2b(float f){
  union { __bf16 h; u16 u; } c; c.h = (__bf16)f; return c.u;
}
__device__ __forceinline__ float upk(u32 pr, int hi){
  union { u32 u; float f; } c; c.u = hi ? (pr & 0xFFFF0000u) : (pr << 16); return c.f;
}
__device__ __forceinline__ float rowsum16(float x){
  x += __shfl_xor(x, 1);
  x += __shfl_xor(x, 2);
  x += __shfl_xor(x, 4);
  x += __shfl_xor(x, 8);
  return x;
}
// 8 consecutive fp32 -> bf16x8 A-fragment chunk
__device__ __forceinline__ bf16x8 cvt8(const float* __restrict__ s){
  f32x4 x0 = *(const f32x4*)s;
  f32x4 x1 = *(const f32x4*)(s + 4);
  bf16x8 r;
  r[0]=(short)f2b(x0[0]); r[1]=(short)f2b(x0[1]);
  r[2]=(short)f2b(x0[2]); r[3]=(short)f2b(x0[3]);
  r[4]=(short)f2b(x1[0]); r[5]=(short)f2b(x1[1]);
  r[6]=(short)f2b(x1[2]); r[7]=(short)f2b(x1[3]);
  return r;
}

// async global->LDS, 16 B per lane (dest = uniform base + lane*16, src per-lane)
__device__ __forceinline__ void glds16(const u16* g, u16* l){
  __builtin_amdgcn_global_load_lds(
      (const __attribute__((address_space(1))) void*)g,
      (__attribute__((address_space(3))) void*)l, 16, 0, 0);
}
// Stage one 128x128 bf16 B matrix (32 KiB, fragment-order = lane-linear) into LDS.
// Completion = next __syncthreads() (its vmcnt(0) drain is the staging wait).
__device__ __forceinline__ void stageB(const u16* __restrict__ packB, int m,
                                       u16* __restrict__ bst, int wave, int lane){
  const u16* src = packB + m*16384 + wave*512 + lane*8;
  u16*       dst = bst   + wave*512;          // wave-uniform; HW adds lane*16B
  #pragma unroll
  for (int k = 0; k < 8; k++)
    glds16(src + k*2048, dst + k*2048);
}

// 16x128 @ 128x128 GEMM: A frags (4 K-tiles) vs B fragments staged in LDS.
__device__ __forceinline__ void gemm16(const bf16x8 a[4], const u16* __restrict__ Blds,
                                       int lane, f32x4 C[8]){
  const bf16x8* Bf = (const bf16x8*)Blds;
  #pragma unroll
  for (int nt = 0; nt < 8; nt++){
    f32x4 c = {0.f, 0.f, 0.f, 0.f};
    #pragma unroll
    for (int kt = 0; kt < 4; kt++){
      bf16x8 b = Bf[(nt*4 + kt)*64 + lane];   // ds_read_b128, contiguous
      c = __builtin_amdgcn_mfma_f32_16x16x32_bf16(a[kt], b, c, 0, 0, 0);
    }
    C[nt] = c;
  }
}

// ---------------- prep: pack weights (fp32 -> bf16, gamma FOLDED) + fp32 vectors ----
// packB layout: mat m (0..11), fragment fi = nt*4+kt, lane, j:
//   packB[m*16384 + fi*512 + lane*8 + j] = Bg[k][n],  k = kt*32+(lane>>4)*8+j, n = nt*16+(lane&15)
// mats 0..5 (fwd, X @ W^T):  Bg[k][n] = src[n*128+k]   (mats 1-4: * gamma[k])
// mats 6..11 (bwd, G @ W):   Bg[k][n] = src[k*128+n]   (mats 7-10: * gamma[n])
// vecs: [0..511] sin embed, [512..1023] b' = bl + Wl@beta, [1024..1151] b_in,
//       [1152..1279] b_out
__global__ void prep_kernel(const float* __restrict__ t,   const float* __restrict__ W_in,
                            const float* __restrict__ b_in,const float* __restrict__ fw,
                            const float* __restrict__ fb,  const float* __restrict__ gamma,
                            const float* __restrict__ beta,const float* __restrict__ Wl,
                            const float* __restrict__ bl,  const float* __restrict__ W_out,
                            const float* __restrict__ b_out,
                            u16* __restrict__ packB, float* __restrict__ vecs)
{
  int bid = blockIdx.x, tid = threadIdx.x;
  if (bid < 768){
    int e    = bid*256 + tid;       // 0..196607
    int m    = e >> 14;             // matrix 0..11
    int r    = e & 16383;
    int fi   = r >> 9;              // nt*4+kt
    int lane = (r >> 3) & 63;
    int j    = r & 7;
    int nt = fi >> 2, kt = fi & 3;
    int k = kt*32 + (lane >> 4)*8 + j;
    int n = nt*16 + (lane & 15);
    const float* src; bool tr;
    if      (m == 0){ src = W_in;              tr = true;  }
    else if (m <= 4){ src = Wl + (m-1)*16384;  tr = true;  }
    else if (m == 5){ src = W_out;             tr = true;  }
    else if (m == 6){ src = W_out;             tr = false; }
    else if (m <=10){ src = Wl + (m-7)*16384;  tr = false; }
    else            { src = W_in;              tr = false; }
    float v = tr ? src[n*128 + k] : src[k*128 + n];
    if      (m >= 1 && m <= 4)  v *= gamma[(m-1)*128 + k];   // fwd: scale contraction dim
    else if (m >= 7 && m <= 10) v *= gamma[(m-7)*128 + n];   // bwd: scale output dim
    packB[e] = f2b(v);
  } else if (bid < 770){
    int idx = (bid - 768)*256 + tid;   // 0..511: time embed
    vecs[idx] = sinf(t[0] * fw[idx] + fb[idx]);
  } else if (bid < 772){
    int gid = (bid - 770)*256 + tid;   // 0..511: b'[i][o] = bl[i][o] + sum_k beta[i][k]*Wl[i][o][k]
    int i = gid >> 7, o = gid & 127;
    const float* Wr = Wl + i*16384 + o*128;
    const float* be = beta + i*128;
    float acc = bl[gid];
    for (int k2 = 0; k2 < 128; k2++) acc += be[k2] * Wr[k2];
    vecs[512 + gid] = acc;
  } else {
    if (tid < 128) vecs[1024 + tid]        = b_in[tid];
    else           vecs[1152 + (tid-128)]  = b_out[tid-128];
  }
}

// ---------------- fused forward + VJP ----------------
// Round 11: consolidation. Best measured config (r3: (256,2), no cap, no
// spill, sv in LDS, 210us) + the verified-correct work reductions from
// r5/r7: gamma folded into packB, beta into b' (absmax unchanged at r7's
// 0.046875), mus/invs checkpoint RESTORED (regs are free at (256,2); avoids
// the bwd stat-recompute pass). The (256,3) route is closed: r4/r7 both show
// cap 170 unified < true demand ~190 -> spill (+150MB HBM), and LDS 54272
// rounds to 55296 (2KB gran) so 3 blocks never fit anyway (r7 occ=21.7).
// Register model (calibrated r3-r7): waves/SIMD = floor(512/(arch+acc));
// natural 128+64 -> 2/SIMD. Spill tripwire: hbm_bytes ~2.2e8.
__global__ __launch_bounds__(256, 2)
void fused_vf(const float* __restrict__ p, const float* __restrict__ w,
              const u16* __restrict__ packB, const float* __restrict__ vecs,
              float* __restrict__ dp_out, float* __restrict__ dw_out)
{
  __shared__ __align__(16) u16  exch[4 * 16 * EX_STRIDE];
  __shared__ __align__(16) u16  bstage[16384];
  __shared__ float sv[1024];

  const int tid  = threadIdx.x;
  const int wave = tid >> 6, lane = tid & 63;
  const int l15  = lane & 15, quad = lane >> 4;
  u16* ex = exch + wave * 16 * EX_STRIDE;

  stageB(packB, 0, bstage, wave, lane);          // B0 in flight
  for (int idx = tid; idx < 1024; idx += 256) sv[idx] = vecs[idx];
  const float* sS   = sv;          // [4][128] sin embed
  const float* sBl  = sv + 512;    // [4][128] b' (beta folded)
  const float* gBin  = vecs + 1024; // [128] global (used once)
  const float* gBout = vecs + 1152; // [128] global (used once)

  const long rowBase = (long)blockIdx.x * 64 + wave * 16;

  // backward checkpoints
  u32   sp_ck[4][8][2];  // sp_i bf16-packed along C reg dim (64 regs)
  float mus[4][4];       // LN mean per (layer, reg-row)
  float invs[4][4];      // LN inv-std

  bf16x8 a[4];
  f32x4  C[8];

  // ---- forward: h0 = p @ W_in^T + b_in ----
  {
    const float* pr = p + (size_t)(rowBase + l15)*128 + quad*8;
    #pragma unroll
    for (int kt = 0; kt < 4; kt++) a[kt] = cvt8(pr + kt*32);
  }
  __syncthreads();                               // sv + B0 staged
  gemm16(a, bstage, lane, C);
  #pragma unroll
  for (int nt = 0; nt < 8; nt++){
    float bv = gBin[nt*16 + l15];                // 8 global loads, once per kernel
    #pragma unroll
    for (int r = 0; r < 4; r++) C[nt][r] += bv;
  }

  // ---- forward layers ----
  #pragma unroll
  for (int i = 0; i < 4; i++){
    __syncthreads();                             // A: bstage reads done
    stageB(packB, 1+i, bstage, wave, lane);      // next B hides under compute
    float sum[4] = {0,0,0,0}, ssq[4] = {0,0,0,0};
    #pragma unroll
    for (int nt = 0; nt < 8; nt++){
      float se = sS[i*128 + nt*16 + l15];
      #pragma unroll
      for (int r = 0; r < 4; r++){
        float x  = C[nt][r] + se;                 // a_i
        float e  = __expf(-fabsf(x));
        float li = __logf(1.0f + e);
        float sp = fmaxf(x, 0.0f) + li;           // softplus
        u16 sb = f2b(sp);                         // checkpoint sp
        if (r & 1) sp_ck[i][nt][r>>1] |= ((u32)sb) << 16; else sp_ck[i][nt][r>>1] = sb;
        sum[r] += sp; ssq[r] += sp*sp;
        C[nt][r] = sp;                            // u_i in place
      }
    }
    float mu[4], inv[4];
    #pragma unroll
    for (int r = 0; r < 4; r++){
      float m1 = rowsum16(sum[r]) * (1.0f/128.0f);
      float m2 = rowsum16(ssq[r]) * (1.0f/128.0f);
      float var = m2 - m1*m1;
      mu[r] = m1; inv[r] = rsqrtf(fmaxf(var, 0.0f) + LN_EPS);
      mus[i][r] = m1; invs[i][r] = inv[r];
    }
    #pragma unroll
    for (int nt = 0; nt < 8; nt++)
      #pragma unroll
      for (int r = 0; r < 4; r++){
        float xh = (C[nt][r] - mu[r]) * inv[r];   // gamma/beta folded into B/b'
        ex[(quad*4 + r)*EX_STRIDE + nt*16 + l15] = f2b(xh);
      }
    __syncthreads();                             // B: exch + staging ready
    {
      const u16* rp = ex + l15*EX_STRIDE + quad*8;
      #pragma unroll
      for (int kt = 0; kt < 4; kt++) a[kt] = *(const bf16x8*)(rp + kt*32);
    }
    gemm16(a, bstage, lane, C);
    #pragma unroll
    for (int nt = 0; nt < 8; nt++){
      float bv = sBl[i*128 + nt*16 + l15];        // b' = bl + Wl@beta
      #pragma unroll
      for (int r = 0; r < 4; r++) C[nt][r] += bv;
    }
  }

  // ---- forward head: dp = h4 @ W_out^T + b_out ----
  __syncthreads();                               // A
  stageB(packB, 5, bstage, wave, lane);
  #pragma unroll
  for (int nt = 0; nt < 8; nt++)
    #pragma unroll
    for (int r = 0; r < 4; r++)
      ex[(quad*4 + r)*EX_STRIDE + nt*16 + l15] = f2b(C[nt][r]);
  __syncthreads();                               // B
  {
    const u16* rp = ex + l15*EX_STRIDE + quad*8;
    #pragma unroll
    for (int kt = 0; kt < 4; kt++) a[kt] = *(const bf16x8*)(rp + kt*32);
  }
  gemm16(a, bstage, lane, C);
  {
    float* gp = dp_out + (size_t)rowBase*128;
    #pragma unroll
    for (int nt = 0; nt < 8; nt++){
      float bv = gBout[nt*16 + l15];
      #pragma unroll
      for (int r = 0; r < 4; r++)
        gp[(size_t)(quad*4 + r)*128 + nt*16 + l15] = C[nt][r] + bv;
    }
  }

  // ---- backward: g_h4 = w @ W_out ----
  __syncthreads();                               // A
  stageB(packB, 6, bstage, wave, lane);
  {
    const float* wr = w + (size_t)(rowBase + l15)*128 + quad*8;
    #pragma unroll
    for (int kt = 0; kt < 4; kt++) a[kt] = cvt8(wr + kt*32);
  }
  __syncthreads();                               // B (w-load latency covered staging)
  gemm16(a, bstage, lane, C);
  __syncthreads();                               // A
  stageB(packB, 10, bstage, wave, lane);         // first bwd-layer B

  #pragma unroll
  for (int ii = 0; ii < 4; ii++){
    const int i = 3 - ii;
    #pragma unroll
    for (int nt = 0; nt < 8; nt++)
      #pragma unroll
      for (int r = 0; r < 4; r++)
        ex[(quad*4 + r)*EX_STRIDE + nt*16 + l15] = f2b(C[nt][r]);
    __syncthreads();                             // B: exch + staging ready
    {
      const u16* rp = ex + l15*EX_STRIDE + quad*8;
      #pragma unroll
      for (int kt = 0; kt < 4; kt++) a[kt] = *(const bf16x8*)(rp + kt*32);
    }
    gemm16(a, bstage, lane, C);                  // g_xh = g_h @ (Wl*gamma)  [folded]
    __syncthreads();                             // A: bstage reads done
    stageB(packB, (ii < 3) ? (7 + (2 - ii)) : 11, bstage, wave, lane);
    // LN backward from sp-checkpoint (mu/inv checkpointed; gamma folded)
    float s1[4] = {0,0,0,0}, s2[4] = {0,0,0,0};
    #pragma unroll
    for (int nt = 0; nt < 8; nt++)
      #pragma unroll
      for (int r = 0; r < 4; r++){
        float sp = upk(sp_ck[i][nt][r>>1], r & 1);
        float xh = (sp - mus[i][r]) * invs[i][r];
        float gx = C[nt][r];                      // g_xhat (direct, gamma folded)
        s1[r] += gx; s2[r] += gx * xh;
        C[nt][r] = gx;
      }
    float m1[4], m2[4];
    #pragma unroll
    for (int r = 0; r < 4; r++){
      m1[r] = rowsum16(s1[r]) * (1.0f/128.0f);
      m2[r] = rowsum16(s2[r]) * (1.0f/128.0f);
    }
    #pragma unroll
    for (int nt = 0; nt < 8; nt++)
      #pragma unroll
      for (int r = 0; r < 4; r++){
        float sp = upk(sp_ck[i][nt][r>>1], r & 1);
        float xh = (sp - mus[i][r]) * invs[i][r];
        float sg = 1.0f - __expf(-sp);            // sigmoid(a) = 1 - exp(-softplus(a))
        float gu = invs[i][r] * (C[nt][r] - m1[r] - xh * m2[r]);
        C[nt][r] = gu * sg;                       // g_a == g_h(prev layer)
      }
  }

  // ---- backward tail: g_p = g @ W_in ; dw = -g_p ----
  #pragma unroll
  for (int nt = 0; nt < 8; nt++)
    #pragma unroll
    for (int r = 0; r < 4; r++)
      ex[(quad*4 + r)*EX_STRIDE + nt*16 + l15] = f2b(C[nt][r]);
  __syncthreads();                               // B: exch + staging(11) ready
  {
    const u16* rp = ex + l15*EX_STRIDE + quad*8;
    #pragma unroll
    for (int kt = 0; kt < 4; kt++) a[kt] = *(const bf16x8*)(rp + kt*32);
  }
  gemm16(a, bstage, lane, C);
  {
    float* gp = dw_out + (size_t)rowBase*128;
    #pragma unroll
    for (int nt = 0; nt < 8; nt++)
      #pragma unroll
      for (int r = 0; r < 4; r++)
        gp[(size_t)(quad*4 + r)*128 + nt*16 + l15] = -C[nt][r];
  }
}

extern "C" void kernel_launch(void* const* d_in, const int* in_sizes, int n_in,
                              void* d_out, int out_size, void* d_ws, size_t ws_size,
                              hipStream_t stream)
{
  const float* t     = (const float*)d_in[0];
  const float* p     = (const float*)d_in[1];
  const float* w     = (const float*)d_in[2];
  const float* W_in  = (const float*)d_in[3];
  const float* b_in  = (const float*)d_in[4];
  const float* fw    = (const float*)d_in[5];
  const float* fb    = (const float*)d_in[6];
  const float* gamma = (const float*)d_in[7];
  const float* beta  = (const float*)d_in[8];
  const float* Wl    = (const float*)d_in[9];
  const float* bl    = (const float*)d_in[10];
  const float* W_out = (const float*)d_in[11];
  const float* b_out = (const float*)d_in[12];

  u16*   packB = (u16*)d_ws;                           // 12*16384 bf16 = 384 KiB
  float* vecs  = (float*)((char*)d_ws + 12*16384*2);   // 1280 fp32

  prep_kernel<<<773, 256, 0, stream>>>(t, W_in, b_in, fw, fb, gamma, beta,
                                       Wl, bl, W_out, b_out, packB, vecs);

  float* dp = (float*)d_out;
  float* dw = (float*)d_out + (size_t)NB * 128;
  fused_vf<<<NB/64, 256, 0, stream>>>(p, w, packB, vecs, dp, dw);
}

// Round 9
// 356.336 us; speedup vs baseline: 1.1538x; 1.0833x over previous
//
#include <hip/hip_runtime.h>

typedef unsigned short u16;
typedef unsigned int   u32;
typedef __attribute__((ext_vector_type(8))) short bf16x8;
typedef __attribute__((ext_vector_type(4))) float f32x4;
typedef __attribute__((ext_vector_type(2))) unsigned int u32x2;

#define NB 131072               // batch rows
#define LN_EPS 1e-5f
#define EX_STRIDE 136           // 128+8 pad; S%8==0 keeps b64/b128 alignment, 2-way bank alias only

// Native RNE fp32->bf16 (compiler emits packed cvt on gfx950)
__device__ __forceinline__ u16 f2b(float f){
  union { __bf16 h; u16 u; } c; c.h = (__bf16)f; return c.u;
}
__device__ __forceinline__ u32 pk2(float a, float b){
  return (u32)f2b(a) | ((u32)f2b(b) << 16);
}
__device__ __forceinline__ float upk(u32 pr, int hi){
  union { u32 u; float f; } c; c.u = hi ? (pr & 0xFFFF0000u) : (pr << 16); return c.f;
}
// feature-sum across quads (features live in-thread + lane bits 4,5)
__device__ __forceinline__ float qsum(float x){
  x += __shfl_xor(x, 16);
  x += __shfl_xor(x, 32);
  return x;
}
// 8 consecutive fp32 -> bf16x8 fragment chunk
__device__ __forceinline__ bf16x8 cvt8(const float* __restrict__ s){
  f32x4 x0 = *(const f32x4*)s;
  f32x4 x1 = *(const f32x4*)(s + 4);
  bf16x8 r;
  r[0]=(short)f2b(x0[0]); r[1]=(short)f2b(x0[1]);
  r[2]=(short)f2b(x0[2]); r[3]=(short)f2b(x0[3]);
  r[4]=(short)f2b(x1[0]); r[5]=(short)f2b(x1[1]);
  r[6]=(short)f2b(x1[2]); r[7]=(short)f2b(x1[3]);
  return r;
}

// async global->LDS, 16 B per lane (dest = uniform base + lane*16, src per-lane)
__device__ __forceinline__ void glds16(const u16* g, u16* l){
  __builtin_amdgcn_global_load_lds(
      (const __attribute__((address_space(1))) void*)g,
      (__attribute__((address_space(3))) void*)l, 16, 0, 0);
}
// Stage one 128x128 bf16 weight matrix (32 KiB, fragment-order = lane-linear) into LDS.
// Completion = next __syncthreads() (its vmcnt(0) drain is the staging wait).
__device__ __forceinline__ void stageB(const u16* __restrict__ packB, int m,
                                       u16* __restrict__ bst, int wave, int lane){
  const u16* src = packB + m*16384 + wave*512 + lane*8;
  u16*       dst = bst   + wave*512;          // wave-uniform; HW adds lane*16B
  #pragma unroll
  for (int k = 0; k < 8; k++)
    glds16(src + k*2048, dst + k*2048);
}

// SWAPPED 16x128 @ 128x128 GEMM: weight frags (LDS) as A-operand, activation
// frags (regs) as B-operand -> C holds the TRANSPOSED output: batch row = l15,
// feature = mt*16 + quad*4 + r. The existing packB B-fragment layout, read as
// an A-fragment, is exactly W (fwd mats) / W^T (bwd mats) -- prep unchanged.
__device__ __forceinline__ void gemm16s(const bf16x8 x[4], const u16* __restrict__ Blds,
                                        int lane, f32x4 C[8]){
  const bf16x8* Wf = (const bf16x8*)Blds;
  #pragma unroll
  for (int mt = 0; mt < 8; mt++){
    f32x4 c = {0.f, 0.f, 0.f, 0.f};
    #pragma unroll
    for (int kt = 0; kt < 4; kt++){
      bf16x8 wfrag = Wf[(mt*4 + kt)*64 + lane];   // ds_read_b128, contiguous
      c = __builtin_amdgcn_mfma_f32_16x16x32_bf16(wfrag, x[kt], c, 0, 0, 0);
    }
    C[mt] = c;
  }
}

// ---------------- prep: pack weights (fp32 -> bf16, gamma FOLDED) + fp32 vectors ----
// UNCHANGED from round 8 (verified passing): the B-fragment packing doubles as
// the A-fragment of W / W^T under the operand swap (lane layouts are mutual
// transposes), so the same packB serves the swapped GEMM.
// vecs: [0..511] sin embed, [512..1023] b' = bl + Wl@beta, [1024..1151] b_in,
//       [1152..1279] b_out
__global__ void prep_kernel(const float* __restrict__ t,   const float* __restrict__ W_in,
                            const float* __restrict__ b_in,const float* __restrict__ fw,
                            const float* __restrict__ fb,  const float* __restrict__ gamma,
                            const float* __restrict__ beta,const float* __restrict__ Wl,
                            const float* __restrict__ bl,  const float* __restrict__ W_out,
                            const float* __restrict__ b_out,
                            u16* __restrict__ packB, float* __restrict__ vecs)
{
  int bid = blockIdx.x, tid = threadIdx.x;
  if (bid < 768){
    int e    = bid*256 + tid;       // 0..196607
    int m    = e >> 14;             // matrix 0..11
    int r    = e & 16383;
    int fi   = r >> 9;              // nt*4+kt
    int lane = (r >> 3) & 63;
    int j    = r & 7;
    int nt = fi >> 2, kt = fi & 3;
    int k = kt*32 + (lane >> 4)*8 + j;
    int n = nt*16 + (lane & 15);
    const float* src; bool tr;
    if      (m == 0){ src = W_in;              tr = true;  }
    else if (m <= 4){ src = Wl + (m-1)*16384;  tr = true;  }
    else if (m == 5){ src = W_out;             tr = true;  }
    else if (m == 6){ src = W_out;             tr = false; }
    else if (m <=10){ src = Wl + (m-7)*16384;  tr = false; }
    else            { src = W_in;              tr = false; }
    float v = tr ? src[n*128 + k] : src[k*128 + n];
    if      (m >= 1 && m <= 4)  v *= gamma[(m-1)*128 + k];   // fwd: scale contraction dim
    else if (m >= 7 && m <= 10) v *= gamma[(m-7)*128 + n];   // bwd: scale output dim
    packB[e] = f2b(v);
  } else if (bid < 770){
    int idx = (bid - 768)*256 + tid;   // 0..511: time embed
    vecs[idx] = sinf(t[0] * fw[idx] + fb[idx]);
  } else if (bid < 772){
    int gid = (bid - 770)*256 + tid;   // 0..511: b'[i][o] = bl[i][o] + sum_k beta[i][k]*Wl[i][o][k]
    int i = gid >> 7, o = gid & 127;
    const float* Wr = Wl + i*16384 + o*128;
    const float* be = beta + i*128;
    float acc = bl[gid];
    for (int k2 = 0; k2 < 128; k2++) acc += be[k2] * Wr[k2];
    vecs[512 + gid] = acc;
  } else {
    if (tid < 128) vecs[1024 + tid]        = b_in[tid];
    else           vecs[1152 + (tid-128)]  = b_out[tid-128];
  }
}

// ---------------- fused forward + VJP ----------------
// Round 12: swapped-operand GEMM. C is transposed (batch=l15, feature=quad/r/mt)
// so: LN reduces per-row via 31 in-thread adds + 2 shfl_xor (was 32 shfls);
// the LDS exchange writes 4 consecutive features -> 8 ds_write_b64 + paired
// bf16 packs (was 32 ds_write_b16 + 32 scalar f2b); se/b'/output all f32x4
// vectorized. mus/invs shrink 32->8 regs (per-row scalars). Barrier/staging
// schedule identical to r8 (proven). prep/packB unchanged.
// Spill tripwire: hbm_bytes ~2.3e8; VGPR expected ~110.
__global__ __launch_bounds__(256, 2)
void fused_vf(const float* __restrict__ p, const float* __restrict__ w,
              const u16* __restrict__ packB, const float* __restrict__ vecs,
              float* __restrict__ dp_out, float* __restrict__ dw_out)
{
  __shared__ __align__(16) u16  exch[4 * 16 * EX_STRIDE];
  __shared__ __align__(16) u16  bstage[16384];
  __shared__ __align__(16) float sv[1024];

  const int tid  = threadIdx.x;
  const int wave = tid >> 6, lane = tid & 63;
  const int l15  = lane & 15, quad = lane >> 4;
  u16* ex = exch + wave * 16 * EX_STRIDE;
  u16*       exw = ex + l15*EX_STRIDE + quad*4;   // write: 4 consecutive features per mt
  const u16* exr = ex + l15*EX_STRIDE + quad*8;   // read: bf16x8 fragment per kt

  stageB(packB, 0, bstage, wave, lane);          // B0 in flight
  for (int idx = tid; idx < 1024; idx += 256) sv[idx] = vecs[idx];
  const float* sS    = sv;          // [4][128] sin embed
  const float* sBl   = sv + 512;    // [4][128] b' (beta folded)
  const float* gBin  = vecs + 1024; // [128] global (used once)
  const float* gBout = vecs + 1152; // [128] global (used once)

  const long rowBase = (long)blockIdx.x * 64 + wave * 16;

  // backward checkpoints
  u32   sp_ck[4][8][2];  // sp bf16-packed along r (feature) dim (64 regs)
  float mus[4];          // LN mean per layer (scalar per batch row now)
  float invs[4];         // LN inv-std

  bf16x8 x[4];
  f32x4  C[8];

  // ---- forward: h0^T = W_in (.) p : x = p row fragment ----
  {
    const float* pr = p + (size_t)(rowBase + l15)*128 + quad*8;
    #pragma unroll
    for (int kt = 0; kt < 4; kt++) x[kt] = cvt8(pr + kt*32);
  }
  __syncthreads();                               // sv + B0 staged
  gemm16s(x, bstage, lane, C);
  #pragma unroll
  for (int mt = 0; mt < 8; mt++)
    C[mt] += *(const f32x4*)(gBin + mt*16 + quad*4);

  // ---- forward layers ----
  #pragma unroll
  for (int i = 0; i < 4; i++){
    __syncthreads();                             // A: bstage reads done
    stageB(packB, 1+i, bstage, wave, lane);      // next W hides under compute
    float sum = 0.f, ssq = 0.f;
    #pragma unroll
    for (int mt = 0; mt < 8; mt++){
      f32x4 se = *(const f32x4*)(sS + i*128 + mt*16 + quad*4);
      #pragma unroll
      for (int r = 0; r < 4; r++){
        float a_ = C[mt][r] + se[r];              // a_i
        float e  = __expf(-fabsf(a_));
        float sp = fmaxf(a_, 0.0f) + __logf(1.0f + e);  // softplus
        u16 sb = f2b(sp);                         // checkpoint sp
        if (r & 1) sp_ck[i][mt][r>>1] |= ((u32)sb) << 16; else sp_ck[i][mt][r>>1] = sb;
        sum += sp; ssq += sp*sp;
        C[mt][r] = sp;
      }
    }
    float m1 = qsum(sum) * (1.0f/128.0f);
    float m2 = qsum(ssq) * (1.0f/128.0f);
    float inv = rsqrtf(fmaxf(m2 - m1*m1, 0.0f) + LN_EPS);
    mus[i] = m1; invs[i] = inv;
    #pragma unroll
    for (int mt = 0; mt < 8; mt++){
      u32x2 v;
      v[0] = pk2((C[mt][0]-m1)*inv, (C[mt][1]-m1)*inv);
      v[1] = pk2((C[mt][2]-m1)*inv, (C[mt][3]-m1)*inv);
      *(u32x2*)(exw + mt*16) = v;                 // ds_write_b64
    }
    __syncthreads();                             // B: exch + staging ready
    #pragma unroll
    for (int kt = 0; kt < 4; kt++) x[kt] = *(const bf16x8*)(exr + kt*32);
    gemm16s(x, bstage, lane, C);
    #pragma unroll
    for (int mt = 0; mt < 8; mt++)
      C[mt] += *(const f32x4*)(sBl + i*128 + mt*16 + quad*4);
  }

  // ---- forward head: dp^T = W_out (.) h4 ----
  __syncthreads();                               // A
  stageB(packB, 5, bstage, wave, lane);
  #pragma unroll
  for (int mt = 0; mt < 8; mt++){
    u32x2 v;
    v[0] = pk2(C[mt][0], C[mt][1]);
    v[1] = pk2(C[mt][2], C[mt][3]);
    *(u32x2*)(exw + mt*16) = v;
  }
  __syncthreads();                               // B
  #pragma unroll
  for (int kt = 0; kt < 4; kt++) x[kt] = *(const bf16x8*)(exr + kt*32);
  gemm16s(x, bstage, lane, C);
  {
    float* gp = dp_out + (size_t)(rowBase + l15)*128;
    #pragma unroll
    for (int mt = 0; mt < 8; mt++){
      f32x4 o = C[mt] + *(const f32x4*)(gBout + mt*16 + quad*4);
      *(f32x4*)(gp + mt*16 + quad*4) = o;         // global_store_dwordx4
    }
  }

  // ---- backward: g_h4^T = W_out^T (.) w ----
  __syncthreads();                               // A
  stageB(packB, 6, bstage, wave, lane);
  {
    const float* wr = w + (size_t)(rowBase + l15)*128 + quad*8;
    #pragma unroll
    for (int kt = 0; kt < 4; kt++) x[kt] = cvt8(wr + kt*32);
  }
  __syncthreads();                               // B (w-load latency covered staging)
  gemm16s(x, bstage, lane, C);
  __syncthreads();                               // A
  stageB(packB, 10, bstage, wave, lane);         // first bwd-layer W

  #pragma unroll
  for (int ii = 0; ii < 4; ii++){
    const int i = 3 - ii;
    #pragma unroll
    for (int mt = 0; mt < 8; mt++){
      u32x2 v;
      v[0] = pk2(C[mt][0], C[mt][1]);
      v[1] = pk2(C[mt][2], C[mt][3]);
      *(u32x2*)(exw + mt*16) = v;
    }
    __syncthreads();                             // B: exch + staging ready
    #pragma unroll
    for (int kt = 0; kt < 4; kt++) x[kt] = *(const bf16x8*)(exr + kt*32);
    gemm16s(x, bstage, lane, C);                 // g_xh^T = (Wl*gamma)^T (.) g
    __syncthreads();                             // A: bstage reads done
    stageB(packB, (ii < 3) ? (7 + (2 - ii)) : 11, bstage, wave, lane);
    // LN backward from sp-checkpoint (scalar stats per batch row)
    float s1 = 0.f, s2 = 0.f;
    #pragma unroll
    for (int mt = 0; mt < 8; mt++)
      #pragma unroll
      for (int r = 0; r < 4; r++){
        float sp = upk(sp_ck[i][mt][r>>1], r & 1);
        float xh = (sp - mus[i]) * invs[i];
        float gx = C[mt][r];                      // g_xhat (gamma folded)
        s1 += gx; s2 += gx * xh;
      }
    float m1 = qsum(s1) * (1.0f/128.0f);
    float m2 = qsum(s2) * (1.0f/128.0f);
    #pragma unroll
    for (int mt = 0; mt < 8; mt++)
      #pragma unroll
      for (int r = 0; r < 4; r++){
        float sp = upk(sp_ck[i][mt][r>>1], r & 1);
        float xh = (sp - mus[i]) * invs[i];
        float sg = 1.0f - __expf(-sp);            // sigmoid(a) = 1 - exp(-softplus(a))
        float gu = invs[i] * (C[mt][r] - m1 - xh * m2);
        C[mt][r] = gu * sg;                       // g_a == g_h(prev layer)
      }
  }

  // ---- backward tail: g_p^T = W_in^T (.) g ; dw = -g_p ----
  #pragma unroll
  for (int mt = 0; mt < 8; mt++){
    u32x2 v;
    v[0] = pk2(C[mt][0], C[mt][1]);
    v[1] = pk2(C[mt][2], C[mt][3]);
    *(u32x2*)(exw + mt*16) = v;
  }
  __syncthreads();                               // B: exch + staging(11) ready
  #pragma unroll
  for (int kt = 0; kt < 4; kt++) x[kt] = *(const bf16x8*)(exr + kt*32);
  gemm16s(x, bstage, lane, C);
  {
    float* gp = dw_out + (size_t)(rowBase + l15)*128;
    #pragma unroll
    for (int mt = 0; mt < 8; mt++){
      f32x4 o = -C[mt];
      *(f32x4*)(gp + mt*16 + quad*4) = o;
    }
  }
}

extern "C" void kernel_launch(void* const* d_in, const int* in_sizes, int n_in,
                              void* d_out, int out_size, void* d_ws, size_t ws_size,
                              hipStream_t stream)
{
  const float* t     = (const float*)d_in[0];
  const float* p     = (const float*)d_in[1];
  const float* w     = (const float*)d_in[2];
  const float* W_in  = (const float*)d_in[3];
  const float* b_in  = (const float*)d_in[4];
  const float* fw    = (const float*)d_in[5];
  const float* fb    = (const float*)d_in[6];
  const float* gamma = (const float*)d_in[7];
  const float* beta  = (const float*)d_in[8];
  const float* Wl    = (const float*)d_in[9];
  const float* bl    = (const float*)d_in[10];
  const float* W_out = (const float*)d_in[11];
  const float* b_out = (const float*)d_in[12];

  u16*   packB = (u16*)d_ws;                           // 12*16384 bf16 = 384 KiB
  float* vecs  = (float*)((char*)d_ws + 12*16384*2);   // 1280 fp32

  prep_kernel<<<773, 256, 0, stream>>>(t, W_in, b_in, fw, fb, gamma, beta,
                                       Wl, bl, W_out, b_out, packB, vecs);

  float* dp = (float*)d_out;
  float* dw = (float*)d_out + (size_t)NB * 128;
  fused_vf<<<NB/64, 256, 0, stream>>>(p, w, packB, vecs, dp, dw);
}